// Round 1
// baseline (725.617 us; speedup 1.0000x reference)
//
#include <hip/hip_runtime.h>
#include <math.h>

#define N_NODES 50000
#define N_EDGES 800000
#define N_GRAPHS 512
#define IN_DIM 126
#define DIM_H 128
#define BN_EPS 1e-5f

// ---------------- pad x [50000,126] -> A [50000,128] (cols 126,127 = 0) ----------------
__global__ void pad_x_kernel(const float* __restrict__ x, float* __restrict__ A) {
    int tid = blockIdx.x * blockDim.x + threadIdx.x;
    if (tid >= N_NODES * 128) return;
    int n = tid >> 7, c = tid & 127;
    A[tid] = (c < IN_DIM) ? x[n * IN_DIM + c] : 0.f;
}

// ---------------- CSR build ----------------
__global__ void count_kernel(const int* __restrict__ dst, int* __restrict__ counts) {
    int e = blockIdx.x * blockDim.x + threadIdx.x;
    if (e < N_EDGES) atomicAdd(&counts[dst[e]], 1);
}

__global__ void scan1_kernel(const int* __restrict__ counts, int* __restrict__ incl,
                             int* __restrict__ bsum) {
    __shared__ int s[512];
    int t = threadIdx.x;
    int i = blockIdx.x * 512 + t;
    int v = (i < N_NODES) ? counts[i] : 0;
    s[t] = v;
    __syncthreads();
    for (int d = 1; d < 512; d <<= 1) {
        int add = (t >= d) ? s[t - d] : 0;
        __syncthreads();
        s[t] += add;
        __syncthreads();
    }
    if (i < N_NODES) incl[i] = s[t];
    if (t == 511) bsum[blockIdx.x] = s[511];
}

__global__ void scan2_kernel(const int* __restrict__ bsum, int* __restrict__ bbase, int nb) {
    __shared__ int s[128];
    int t = threadIdx.x;
    int v = (t < nb) ? bsum[t] : 0;
    s[t] = v;
    __syncthreads();
    for (int d = 1; d < 128; d <<= 1) {
        int add = (t >= d) ? s[t - d] : 0;
        __syncthreads();
        s[t] += add;
        __syncthreads();
    }
    if (t < nb) bbase[t] = s[t] - v;  // exclusive
}

__global__ void offsets_kernel(const int* __restrict__ incl, const int* __restrict__ counts,
                               const int* __restrict__ bbase, int* __restrict__ offsets,
                               int* __restrict__ cursor) {
    int i = blockIdx.x * blockDim.x + threadIdx.x;
    if (i >= N_NODES) return;
    int off = bbase[i >> 9] + incl[i] - counts[i];
    offsets[i] = off;
    cursor[i] = off;
}

__global__ void fill_kernel(const int* __restrict__ src, const int* __restrict__ dst,
                            int* __restrict__ cursor, int* __restrict__ perm) {
    int e = blockIdx.x * blockDim.x + threadIdx.x;
    if (e >= N_EDGES) return;
    int pos = atomicAdd(&cursor[dst[e]], 1);
    perm[pos] = src[e];
}

// ---------------- aggregate: y[n] = h[n] + sum_{e: dst=n} h[src(e)] ----------------
// one wave (64 lanes) per node, each lane owns 2 of 128 dims
__global__ void aggregate_kernel(const float* __restrict__ h, float* __restrict__ y,
                                 const int* __restrict__ offsets, const int* __restrict__ counts,
                                 const int* __restrict__ perm) {
    int wid = (int)((blockIdx.x * blockDim.x + threadIdx.x) >> 6);
    int lane = threadIdx.x & 63;
    if (wid >= N_NODES) return;
    const float2* hp = (const float2*)h;
    int halfidx = wid * 64 + lane;
    float2 acc = hp[halfidx];  // self term
    int off = offsets[wid], cnt = counts[wid];
    for (int e = 0; e < cnt; ++e) {
        int s = perm[off + e];
        float2 v = hp[s * 64 + lane];
        acc.x += v.x;
        acc.y += v.y;
    }
    ((float2*)y)[halfidx] = acc;
}

// ---------------- GEMM: Out = relu( BN( A[:, :K] @ W[K,128] + bias ) ) ----------------
// 64x128 tile, BK=16, 256 threads, 4x8 micro-tile
template <bool HAS_BN>
__global__ __launch_bounds__(256) void gemm_kernel(
    const float* __restrict__ A, const float* __restrict__ W, const float* __restrict__ bias,
    const float* __restrict__ gamma, const float* __restrict__ beta,
    const float* __restrict__ mean, const float* __restrict__ var,
    float* __restrict__ Out, int K) {
    __shared__ float As[16][68];   // [k][row], padded
    __shared__ float Bs[16][128];  // [k][col]
    int t = threadIdx.x;
    int row0 = blockIdx.x * 64;
    int tr = t >> 4, tc = t & 15;
    int r0 = tr * 4, c0 = tc * 8;
    float acc[4][8];
#pragma unroll
    for (int i = 0; i < 4; i++)
#pragma unroll
        for (int j = 0; j < 8; j++) acc[i][j] = 0.f;

    int ar = t >> 2, aq = t & 3;        // A staging: row, quarter
    int bkr = t >> 4, bc = (t & 15) * 8;  // B staging

    for (int k0 = 0; k0 < K; k0 += 16) {
        float4 av = make_float4(0.f, 0.f, 0.f, 0.f);
        int grow = row0 + ar;
        if (grow < N_NODES) av = *(const float4*)&A[grow * 128 + k0 + aq * 4];
        As[aq * 4 + 0][ar] = av.x;
        As[aq * 4 + 1][ar] = av.y;
        As[aq * 4 + 2][ar] = av.z;
        As[aq * 4 + 3][ar] = av.w;

        float4 b0 = make_float4(0.f, 0.f, 0.f, 0.f), b1 = b0;
        if (k0 + bkr < K) {
            b0 = *(const float4*)&W[(k0 + bkr) * 128 + bc];
            b1 = *(const float4*)&W[(k0 + bkr) * 128 + bc + 4];
        }
        *(float4*)&Bs[bkr][bc] = b0;
        *(float4*)&Bs[bkr][bc + 4] = b1;
        __syncthreads();

#pragma unroll
        for (int k = 0; k < 16; ++k) {
            float4 a4 = *(const float4*)&As[k][r0];
            float b[8];
            *(float4*)&b[0] = *(const float4*)&Bs[k][c0];
            *(float4*)&b[4] = *(const float4*)&Bs[k][c0 + 4];
            float a[4] = {a4.x, a4.y, a4.z, a4.w};
#pragma unroll
            for (int i = 0; i < 4; i++)
#pragma unroll
                for (int j = 0; j < 8; j++) acc[i][j] = fmaf(a[i], b[j], acc[i][j]);
        }
        __syncthreads();
    }

    // epilogue: per-column scale/shift (BN folded), relu
    float scl[8], sft[8];
#pragma unroll
    for (int j = 0; j < 8; j++) {
        float b = bias[c0 + j];
        if (HAS_BN) {
            float rs = rsqrtf(var[c0 + j] + BN_EPS);
            float g = gamma[c0 + j] * rs;
            scl[j] = g;
            sft[j] = beta[c0 + j] + (b - mean[c0 + j]) * g;
        } else {
            scl[j] = 1.f;
            sft[j] = b;
        }
    }
#pragma unroll
    for (int i = 0; i < 4; i++) {
        int grow = row0 + r0 + i;
        if (grow < N_NODES) {
            float o[8];
#pragma unroll
            for (int j = 0; j < 8; j++) o[j] = fmaxf(fmaf(acc[i][j], scl[j], sft[j]), 0.f);
            *(float4*)&Out[grow * 128 + c0] = *(const float4*)&o[0];
            *(float4*)&Out[grow * 128 + c0 + 4] = *(const float4*)&o[4];
        }
    }
}

// ---------------- global add pool ----------------
__global__ void pool_kernel(const float* __restrict__ h, const int* __restrict__ batch,
                            float* __restrict__ hg) {
    int tid = blockIdx.x * blockDim.x + threadIdx.x;
    int n = tid >> 6, l = tid & 63;
    if (n >= N_NODES) return;
    int g = batch[n];
    float2 v = *(const float2*)&h[n * 128 + l * 2];
    atomicAdd(&hg[g * 128 + l * 2], v.x);
    atomicAdd(&hg[g * 128 + l * 2 + 1], v.y);
}

// ---------------- head: sigmoid(relu(hg @ l1_w + l1_b) @ l2_w + l2_b) ----------------
__global__ void head_kernel(const float* __restrict__ hg, const float* __restrict__ l1w,
                            const float* __restrict__ l1b, const float* __restrict__ l2w,
                            const float* __restrict__ l2b, float* __restrict__ out) {
    __shared__ float row[128];
    int g = blockIdx.x, t = threadIdx.x;  // 64 threads
    *(float2*)&row[t * 2] = *(const float2*)&hg[g * 128 + t * 2];
    __syncthreads();
    float a = l1b[t];
    for (int k = 0; k < 128; k++) a = fmaf(row[k], l1w[k * 64 + t], a);
    a = fmaxf(a, 0.f);
    float p = a * l2w[t];
    for (int d = 32; d; d >>= 1) p += __shfl_down(p, d);
    if (t == 0) out[g] = 1.f / (1.f + expf(-(p + l2b[0])));
}

extern "C" void kernel_launch(void* const* d_in, const int* in_sizes, int n_in,
                              void* d_out, int out_size, void* d_ws, size_t ws_size,
                              hipStream_t stream) {
    (void)in_sizes; (void)n_in; (void)out_size; (void)ws_size;
    const float* x = (const float*)d_in[0];
    const int* ei = (const int*)d_in[1];
    const int* batch = (const int*)d_in[2];
    const float *cw1[3], *cb1[3], *cg[3], *cbe[3], *cme[3], *cva[3], *cw2[3], *cb2[3];
    for (int i = 0; i < 3; i++) {
        int base = 3 + i * 8;
        cw1[i] = (const float*)d_in[base + 0];
        cb1[i] = (const float*)d_in[base + 1];
        cg[i]  = (const float*)d_in[base + 2];
        cbe[i] = (const float*)d_in[base + 3];
        cme[i] = (const float*)d_in[base + 4];
        cva[i] = (const float*)d_in[base + 5];
        cw2[i] = (const float*)d_in[base + 6];
        cb2[i] = (const float*)d_in[base + 7];
    }
    const float* l1w = (const float*)d_in[27];
    const float* l1b = (const float*)d_in[28];
    const float* l2w = (const float*)d_in[29];
    const float* l2b = (const float*)d_in[30];

    char* ws = (char*)d_ws;
    size_t off = 0;
    auto alloc = [&](size_t bytes) -> void* {
        void* p = ws + off;
        off += (bytes + 511) & ~(size_t)511;
        return p;
    };
    float* A = (float*)alloc((size_t)N_NODES * 128 * 4);
    float* B = (float*)alloc((size_t)N_NODES * 128 * 4);
    float* C = (float*)alloc((size_t)N_NODES * 128 * 4);
    float* hg = (float*)alloc((size_t)N_GRAPHS * 128 * 4);
    int* counts  = (int*)alloc((size_t)N_NODES * 4);
    int* incl    = (int*)alloc((size_t)N_NODES * 4);
    int* offsets = (int*)alloc((size_t)N_NODES * 4);
    int* cursor  = (int*)alloc((size_t)N_NODES * 4);
    int* bsum    = (int*)alloc(512 * 4);
    int* bbase   = (int*)alloc(512 * 4);
    int* perm    = (int*)alloc((size_t)N_EDGES * 4);

    const int* src = ei;
    const int* dst = ei + N_EDGES;

    const int NB = (N_NODES + 511) / 512;  // 98

    hipMemsetAsync(counts, 0, (size_t)N_NODES * 4, stream);
    hipMemsetAsync(hg, 0, (size_t)N_GRAPHS * 128 * 4, stream);
    count_kernel<<<(N_EDGES + 255) / 256, 256, 0, stream>>>(dst, counts);
    scan1_kernel<<<NB, 512, 0, stream>>>(counts, incl, bsum);
    scan2_kernel<<<1, 128, 0, stream>>>(bsum, bbase, NB);
    offsets_kernel<<<(N_NODES + 255) / 256, 256, 0, stream>>>(incl, counts, bbase, offsets, cursor);
    fill_kernel<<<(N_EDGES + 255) / 256, 256, 0, stream>>>(src, dst, cursor, perm);
    pad_x_kernel<<<(N_NODES * 128 + 255) / 256, 256, 0, stream>>>(x, A);

    for (int l = 0; l < 3; ++l) {
        aggregate_kernel<<<(N_NODES * 64 + 255) / 256, 256, 0, stream>>>(A, B, offsets, counts, perm);
        int K1 = (l == 0) ? IN_DIM : DIM_H;
        gemm_kernel<true><<<(N_NODES + 63) / 64, 256, 0, stream>>>(
            B, cw1[l], cb1[l], cg[l], cbe[l], cme[l], cva[l], C, K1);
        gemm_kernel<false><<<(N_NODES + 63) / 64, 256, 0, stream>>>(
            C, cw2[l], cb2[l], nullptr, nullptr, nullptr, nullptr, A, DIM_H);
    }
    pool_kernel<<<(N_NODES * 64 + 255) / 256, 256, 0, stream>>>(A, batch, hg);
    head_kernel<<<N_GRAPHS, 64, 0, stream>>>(hg, l1w, l1b, l2w, l2b, (float*)d_out);
}

// Round 2
// 437.582 us; speedup vs baseline: 1.6582x; 1.6582x over previous
//
#include <hip/hip_runtime.h>
#include <math.h>

#define N_NODES 50000
#define N_EDGES 800000
#define N_GRAPHS 512
#define IN_DIM 126
#define DIM_H 128
#define BN_EPS 1e-5f

typedef unsigned int u32;
typedef short short8 __attribute__((ext_vector_type(8)));
typedef float f32x4 __attribute__((ext_vector_type(4)));

__device__ __forceinline__ unsigned short f2bf(float f) {
    u32 u = __float_as_uint(f);
    u += 0x7fffu + ((u >> 16) & 1u);  // RNE
    return (unsigned short)(u >> 16);
}
__device__ __forceinline__ float bflo(u32 u) { return __uint_as_float(u << 16); }
__device__ __forceinline__ float bfhi(u32 u) { return __uint_as_float(u & 0xffff0000u); }
__device__ __forceinline__ u32 pack2(float a, float b) {
    return (u32)f2bf(a) | ((u32)f2bf(b) << 16);
}

// ---------------- pad x [50000,126] fp32 -> A [50000,128] bf16 ----------------
__global__ void pad_x_kernel(const float* __restrict__ x, unsigned short* __restrict__ A) {
    int tid = blockIdx.x * blockDim.x + threadIdx.x;
    int n = tid >> 6, c2 = tid & 63;
    if (n >= N_NODES) return;
    int c = c2 * 2;
    float f0 = (c < IN_DIM) ? x[n * IN_DIM + c] : 0.f;
    float f1 = (c + 1 < IN_DIM) ? x[n * IN_DIM + c + 1] : 0.f;
    ((u32*)A)[tid] = pack2(f0, f1);
}

// ---------------- CSR build ----------------
__global__ void count_kernel(const int* __restrict__ dst, int* __restrict__ counts) {
    int e = blockIdx.x * blockDim.x + threadIdx.x;
    if (e < N_EDGES) atomicAdd(&counts[dst[e]], 1);
}

__global__ void scan1_kernel(const int* __restrict__ counts, int* __restrict__ incl,
                             int* __restrict__ bsum) {
    __shared__ int s[512];
    int t = threadIdx.x;
    int i = blockIdx.x * 512 + t;
    int v = (i < N_NODES) ? counts[i] : 0;
    s[t] = v;
    __syncthreads();
    for (int d = 1; d < 512; d <<= 1) {
        int add = (t >= d) ? s[t - d] : 0;
        __syncthreads();
        s[t] += add;
        __syncthreads();
    }
    if (i < N_NODES) incl[i] = s[t];
    if (t == 511) bsum[blockIdx.x] = s[511];
}

__global__ void scan2_kernel(const int* __restrict__ bsum, int* __restrict__ bbase, int nb) {
    __shared__ int s[128];
    int t = threadIdx.x;
    int v = (t < nb) ? bsum[t] : 0;
    s[t] = v;
    __syncthreads();
    for (int d = 1; d < 128; d <<= 1) {
        int add = (t >= d) ? s[t - d] : 0;
        __syncthreads();
        s[t] += add;
        __syncthreads();
    }
    if (t < nb) bbase[t] = s[t] - v;  // exclusive
}

__global__ void offsets_kernel(const int* __restrict__ incl, const int* __restrict__ counts,
                               const int* __restrict__ bbase, int* __restrict__ offsets,
                               int* __restrict__ cursor) {
    int i = blockIdx.x * blockDim.x + threadIdx.x;
    if (i >= N_NODES) return;
    int off = bbase[i >> 9] + incl[i] - counts[i];
    offsets[i] = off;
    cursor[i] = off;
}

__global__ void fill_kernel(const int* __restrict__ src, const int* __restrict__ dst,
                            int* __restrict__ cursor, int* __restrict__ perm) {
    int e = blockIdx.x * blockDim.x + threadIdx.x;
    if (e >= N_EDGES) return;
    int pos = atomicAdd(&cursor[dst[e]], 1);
    perm[pos] = src[e];
}

// ---------------- aggregate: y[n] = h[n] + sum_{e: dst=n} h[src(e)]  (bf16 rows) ----------
// one wave per node; quarter-wave q owns edge (e+q), lane handles 8 cols (uint4 = 16B)
__global__ void aggregate_kernel(const unsigned short* __restrict__ h,
                                 unsigned short* __restrict__ y,
                                 const int* __restrict__ offsets, const int* __restrict__ counts,
                                 const int* __restrict__ perm) {
    int wid = (int)((blockIdx.x * blockDim.x + threadIdx.x) >> 6);
    if (wid >= N_NODES) return;
    int lane = threadIdx.x & 63;
    int q = lane >> 4, sub = lane & 15;
    float acc[8];
#pragma unroll
    for (int i = 0; i < 8; i++) acc[i] = 0.f;
    int off = offsets[wid], cnt = counts[wid];
    for (int base = 0; base < cnt; base += 64) {
        int rem = cnt - base;
        if (rem > 64) rem = 64;
        int pl = perm[off + base + (lane < rem ? lane : 0)];
        for (int e = 0; e < rem; e += 4) {
            int ei = e + q;
            int s = __shfl(pl, ei);
            if (ei < rem) {
                const uint4 v = *(const uint4*)(h + (size_t)s * 128 + sub * 8);
                acc[0] += bflo(v.x); acc[1] += bfhi(v.x);
                acc[2] += bflo(v.y); acc[3] += bfhi(v.y);
                acc[4] += bflo(v.z); acc[5] += bfhi(v.z);
                acc[6] += bflo(v.w); acc[7] += bfhi(v.w);
            }
        }
    }
#pragma unroll
    for (int i = 0; i < 8; i++) {
        acc[i] += __shfl_xor(acc[i], 16);
        acc[i] += __shfl_xor(acc[i], 32);
    }
    if (q == 0) {
        const uint4 sv = *(const uint4*)(h + (size_t)wid * 128 + sub * 8);
        acc[0] += bflo(sv.x); acc[1] += bfhi(sv.x);
        acc[2] += bflo(sv.y); acc[3] += bfhi(sv.y);
        acc[4] += bflo(sv.z); acc[5] += bfhi(sv.z);
        acc[6] += bflo(sv.w); acc[7] += bfhi(sv.w);
        uint4 o;
        o.x = pack2(acc[0], acc[1]);
        o.y = pack2(acc[2], acc[3]);
        o.z = pack2(acc[4], acc[5]);
        o.w = pack2(acc[6], acc[7]);
        *(uint4*)(y + (size_t)wid * 128 + sub * 8) = o;
    }
}

// ---------------- weight prep: Wt[g][n][k] bf16, BN-folded, chunk-XOR swizzled ----------
struct WArgs {
    const float *w, *b, *g, *be, *m, *v;
    int K, hasBN;
};
struct WArgs6 { WArgs a[6]; };

__global__ void prep_w_kernel(WArgs6 args, unsigned short* __restrict__ Wt,
                              float* __restrict__ shift) {
    int gi = blockIdx.x >> 3;   // gemm index 0..5
    int part = blockIdx.x & 7;
    WArgs A = args.a[gi];
    int t = threadIdx.x;
    int task = part * 256 + t;      // 0..2047
    int n = task & 127, kc = task >> 7;  // kc 0..15 (8-elem k-chunks)
    float scl, sft;
    if (A.hasBN) {
        float rs = rsqrtf(A.v[n] + BN_EPS);
        scl = A.g[n] * rs;
        sft = A.be[n] + (A.b[n] - A.m[n]) * scl;
    } else {
        scl = 1.f;
        sft = A.b[n];
    }
    u32 o[4];
#pragma unroll
    for (int j = 0; j < 4; j++) {
        int k0 = kc * 8 + j * 2;
        float f0 = (k0 < A.K) ? A.w[k0 * 128 + n] * scl : 0.f;
        float f1 = (k0 + 1 < A.K) ? A.w[(k0 + 1) * 128 + n] * scl : 0.f;
        o[j] = pack2(f0, f1);
    }
    unsigned short* dst = Wt + (size_t)gi * 16384 + n * 128 + ((kc ^ (n & 7)) * 8);
    *(uint4*)dst = make_uint4(o[0], o[1], o[2], o[3]);
    if (kc == 0) shift[gi * 128 + n] = sft;
}

// ---------------- GEMM: Out = relu(A @ W' + shift), bf16 in/out, MFMA ----------------
// block: 256 threads (4 waves), 128 rows; wave w -> rows [w*32, w*32+32)
__global__ __launch_bounds__(256) void gemm_mfma_kernel(
    const unsigned short* __restrict__ A, const unsigned short* __restrict__ Wt,
    const float* __restrict__ shift, unsigned short* __restrict__ Out) {
    __shared__ unsigned short Ws[128 * 128];  // 32 KB, swizzled chunks
    __shared__ float sh[128];
    int t = threadIdx.x;
    {
        const float4* src = (const float4*)Wt;
        float4* dst = (float4*)Ws;
#pragma unroll
        for (int i = 0; i < 8; i++) dst[t + i * 256] = src[t + i * 256];
        if (t < 128) sh[t] = shift[t];
    }
    __syncthreads();
    int wave = t >> 6, lane = t & 63;
    int row0 = blockIdx.x * 128 + wave * 32;
    int arow = lane & 15, aq = lane >> 4;  // fragment: row=lane&15, kchunk=lane>>4
    int r0i = row0 + arow; if (r0i > N_NODES - 1) r0i = N_NODES - 1;
    int r1i = row0 + 16 + arow; if (r1i > N_NODES - 1) r1i = N_NODES - 1;
    const unsigned short* a0p = A + (size_t)r0i * 128 + aq * 8;
    const unsigned short* a1p = A + (size_t)r1i * 128 + aq * 8;
    f32x4 acc[2][8];
#pragma unroll
    for (int i = 0; i < 2; i++)
#pragma unroll
        for (int c = 0; c < 8; c++) acc[i][c] = (f32x4){0.f, 0.f, 0.f, 0.f};

#pragma unroll
    for (int s = 0; s < 4; s++) {
        short8 a0 = *(const short8*)(a0p + s * 32);
        short8 a1 = *(const short8*)(a1p + s * 32);
#pragma unroll
        for (int c = 0; c < 8; c++) {
            int n = c * 16 + arow;                  // B col
            int kc = (s * 4 + aq) ^ (n & 7);        // swizzled k-chunk
            short8 b = *(const short8*)&Ws[n * 128 + kc * 8];
            acc[0][c] = __builtin_amdgcn_mfma_f32_16x16x32_bf16(a0, b, acc[0][c], 0, 0, 0);
            acc[1][c] = __builtin_amdgcn_mfma_f32_16x16x32_bf16(a1, b, acc[1][c], 0, 0, 0);
        }
    }
    // C/D layout: col = lane&15, row = (lane>>4)*4 + j
    int ccol = lane & 15, crow4 = (lane >> 4) * 4;
#pragma unroll
    for (int rt = 0; rt < 2; rt++) {
#pragma unroll
        for (int c = 0; c < 8; c++) {
            float s0 = sh[c * 16 + ccol];
#pragma unroll
            for (int j = 0; j < 4; j++) {
                int grow = row0 + rt * 16 + crow4 + j;
                if (grow < N_NODES) {
                    float v = fmaxf(acc[rt][c][j] + s0, 0.f);
                    Out[(size_t)grow * 128 + c * 16 + ccol] = f2bf(v);
                }
            }
        }
    }
}

// ---------------- global add pool (bf16 h -> fp32 hg) ----------------
__global__ void pool_kernel(const unsigned short* __restrict__ h, const int* __restrict__ batch,
                            float* __restrict__ hg) {
    int tid = blockIdx.x * blockDim.x + threadIdx.x;
    int n = tid >> 6, l = tid & 63;
    if (n >= N_NODES) return;
    int g = batch[n];
    u32 v = ((const u32*)h)[n * 64 + l];
    atomicAdd(&hg[g * 128 + l * 2], bflo(v));
    atomicAdd(&hg[g * 128 + l * 2 + 1], bfhi(v));
}

// ---------------- head ----------------
__global__ void head_kernel(const float* __restrict__ hg, const float* __restrict__ l1w,
                            const float* __restrict__ l1b, const float* __restrict__ l2w,
                            const float* __restrict__ l2b, float* __restrict__ out) {
    __shared__ float row[128];
    int g = blockIdx.x, t = threadIdx.x;  // 64 threads
    *(float2*)&row[t * 2] = *(const float2*)&hg[g * 128 + t * 2];
    __syncthreads();
    float a = l1b[t];
    for (int k = 0; k < 128; k++) a = fmaf(row[k], l1w[k * 64 + t], a);
    a = fmaxf(a, 0.f);
    float p = a * l2w[t];
    for (int d = 32; d; d >>= 1) p += __shfl_down(p, d);
    if (t == 0) out[g] = 1.f / (1.f + expf(-(p + l2b[0])));
}

extern "C" void kernel_launch(void* const* d_in, const int* in_sizes, int n_in,
                              void* d_out, int out_size, void* d_ws, size_t ws_size,
                              hipStream_t stream) {
    (void)in_sizes; (void)n_in; (void)out_size; (void)ws_size;
    const float* x = (const float*)d_in[0];
    const int* ei = (const int*)d_in[1];
    const int* batch = (const int*)d_in[2];
    WArgs6 wa;
    for (int i = 0; i < 3; i++) {
        int base = 3 + i * 8;
        const float* w1 = (const float*)d_in[base + 0];
        const float* b1 = (const float*)d_in[base + 1];
        const float* g  = (const float*)d_in[base + 2];
        const float* be = (const float*)d_in[base + 3];
        const float* me = (const float*)d_in[base + 4];
        const float* va = (const float*)d_in[base + 5];
        const float* w2 = (const float*)d_in[base + 6];
        const float* b2 = (const float*)d_in[base + 7];
        wa.a[i * 2] = WArgs{w1, b1, g, be, me, va, (i == 0) ? IN_DIM : DIM_H, 1};
        wa.a[i * 2 + 1] = WArgs{w2, b2, nullptr, nullptr, nullptr, nullptr, DIM_H, 0};
    }
    const float* l1w = (const float*)d_in[27];
    const float* l1b = (const float*)d_in[28];
    const float* l2w = (const float*)d_in[29];
    const float* l2b = (const float*)d_in[30];

    char* ws = (char*)d_ws;
    size_t off = 0;
    auto alloc = [&](size_t bytes) -> void* {
        void* p = ws + off;
        off += (bytes + 511) & ~(size_t)511;
        return p;
    };
    unsigned short* A = (unsigned short*)alloc((size_t)N_NODES * 128 * 2);
    unsigned short* B = (unsigned short*)alloc((size_t)N_NODES * 128 * 2);
    unsigned short* C = (unsigned short*)alloc((size_t)N_NODES * 128 * 2);
    float* hg = (float*)alloc((size_t)N_GRAPHS * 128 * 4);
    unsigned short* Wt = (unsigned short*)alloc((size_t)6 * 16384 * 2);
    float* shift = (float*)alloc(6 * 128 * 4);
    int* counts  = (int*)alloc((size_t)N_NODES * 4);
    int* incl    = (int*)alloc((size_t)N_NODES * 4);
    int* offsets = (int*)alloc((size_t)N_NODES * 4);
    int* cursor  = (int*)alloc((size_t)N_NODES * 4);
    int* bsum    = (int*)alloc(512 * 4);
    int* bbase   = (int*)alloc(512 * 4);
    int* perm    = (int*)alloc((size_t)N_EDGES * 4);

    const int* src = ei;
    const int* dst = ei + N_EDGES;
    const int NB = (N_NODES + 511) / 512;  // 98

    hipMemsetAsync(counts, 0, (size_t)N_NODES * 4, stream);
    hipMemsetAsync(hg, 0, (size_t)N_GRAPHS * 128 * 4, stream);
    count_kernel<<<(N_EDGES + 255) / 256, 256, 0, stream>>>(dst, counts);
    scan1_kernel<<<NB, 512, 0, stream>>>(counts, incl, bsum);
    scan2_kernel<<<1, 128, 0, stream>>>(bsum, bbase, NB);
    offsets_kernel<<<(N_NODES + 255) / 256, 256, 0, stream>>>(incl, counts, bbase, offsets, cursor);
    fill_kernel<<<(N_EDGES + 255) / 256, 256, 0, stream>>>(src, dst, cursor, perm);
    prep_w_kernel<<<48, 256, 0, stream>>>(wa, Wt, shift);
    pad_x_kernel<<<(N_NODES * 64 + 255) / 256, 256, 0, stream>>>(x, A);

    const int GB = (N_NODES + 127) / 128;  // 391
    for (int l = 0; l < 3; ++l) {
        aggregate_kernel<<<(N_NODES * 64 + 255) / 256, 256, 0, stream>>>(A, B, offsets, counts, perm);
        gemm_mfma_kernel<<<GB, 256, 0, stream>>>(B, Wt + (size_t)(l * 2) * 16384,
                                                 shift + (l * 2) * 128, C);
        gemm_mfma_kernel<<<GB, 256, 0, stream>>>(C, Wt + (size_t)(l * 2 + 1) * 16384,
                                                 shift + (l * 2 + 1) * 128, A);
    }
    pool_kernel<<<(N_NODES * 64 + 255) / 256, 256, 0, stream>>>(A, batch, hg);
    head_kernel<<<N_GRAPHS, 64, 0, stream>>>(hg, l1w, l1b, l2w, l2b, (float*)d_out);
}